// Round 2
// baseline (1341.915 us; speedup 1.0000x reference)
//
#include <hip/hip_runtime.h>
#include <hip/hip_bf16.h>

#define MEMD 256
#define ROWS 511   // 256+128+64+32+16+8+4+2+1

__device__ __forceinline__ float sigmf(float x){ return 1.0f/(1.0f+__expf(-x)); }
__device__ __forceinline__ float tanhfast(float x){
  x = fminf(fmaxf(x, -15.0f), 15.0f);
  float e = __expf(2.0f*x);
  return (e-1.0f)/(e+1.0f);
}

// ---------------------------------------------------------------------------
// Init: iou = x @ W_ioux^T + b_ioux + b_iouh; gates -> c0,h0 for both trees.
// Blocks [0,256): pass A (lx) ; [256,512): pass B (rx). One block per row n.
// ---------------------------------------------------------------------------
__global__ void k_init(const int* __restrict__ l_idx, const int* __restrict__ r_idx,
                       const float* __restrict__ emb, const float* __restrict__ W_ioux,
                       const float* __restrict__ b_ioux, const float* __restrict__ b_iouh,
                       float* __restrict__ cmatA, float* __restrict__ matL,
                       float* __restrict__ cmatB, float* __restrict__ matR)
{
  int b = blockIdx.x;
  bool isA = (b < 256);
  int n = isA ? b : b - 256;
  int row = isA ? l_idx[n] : r_idx[n];
  float* crow = (isA ? cmatA : cmatB) + (size_t)n*MEMD;
  float* hrow = (isA ? matL  : matR ) + (size_t)n*MEMD;

  __shared__ float xs[304];
  const float* xr = emb + (size_t)row*300;
  for (int d = threadIdx.x; d < 300; d += 256) xs[d] = xr[d];
  __syncthreads();

  int m = threadIdx.x;
  const float* wi = W_ioux + (size_t)m*300;
  const float* wo = W_ioux + (size_t)(m+256)*300;
  const float* wu = W_ioux + (size_t)(m+512)*300;
  float ai=0.f, ao=0.f, au=0.f;
  for (int d = 0; d < 300; ++d){
    float x = xs[d];
    ai += x*wi[d];
    ao += x*wo[d];
    au += x*wu[d];
  }
  ai += b_ioux[m]     + b_iouh[m];
  ao += b_ioux[m+256] + b_iouh[m+256];
  au += b_ioux[m+512] + b_iouh[m+512];
  float c = sigmf(ai)*tanhfast(au);
  float h = sigmf(ao)*tanhfast(c);
  crow[m] = c; hrow[m] = h;
}

// ---------------------------------------------------------------------------
// One tree level for passes A and B (no attention).
// Blocks [0,half): pass A ; [half,2*half): pass B. One block per output row n.
// ---------------------------------------------------------------------------
__global__ void k_level(const float* __restrict__ W_iouh, const float* __restrict__ b_iouh,
                        const float* __restrict__ W_fh, const float* __restrict__ b_fh,
                        int half, int offPrev, int offCur,
                        float* __restrict__ cmatA, float* __restrict__ matL,
                        float* __restrict__ cmatB, float* __restrict__ matR)
{
  int b = blockIdx.x;
  bool isA = (b < half);
  int n = isA ? b : b - half;
  float* cmat = isA ? cmatA : cmatB;
  float* hmat = isA ? matL  : matR;
  const float* h0 = hmat + (size_t)(offPrev + 2*n)*MEMD;
  const float* h1 = h0 + MEMD;
  const float* c0 = cmat + (size_t)(offPrev + 2*n)*MEMD;
  const float* c1 = c0 + MEMD;

  __shared__ float hs0[256], hs1[256], hss[256];
  int t = threadIdx.x;
  float a0 = h0[t], a1 = h1[t];
  hs0[t] = a0; hs1[t] = a1; hss[t] = a0 + a1;
  __syncthreads();

  const float* wi = W_iouh + (size_t)t*256;
  const float* wo = W_iouh + (size_t)(t+256)*256;
  const float* wu = W_iouh + (size_t)(t+512)*256;
  const float* wf = W_fh   + (size_t)t*256;
  float ai=0.f, ao=0.f, au=0.f, af0=0.f, af1=0.f;
  for (int d = 0; d < 256; ++d){
    float s = hss[d];
    ai += s*wi[d];
    ao += s*wo[d];
    au += s*wu[d];
    float w = wf[d];
    af0 += hs0[d]*w;
    af1 += hs1[d]*w;
  }
  ai += b_iouh[t]; ao += b_iouh[t+256]; au += b_iouh[t+512];
  float bf = b_fh[t];
  float c = sigmf(ai)*tanhfast(au) + sigmf(af0+bf)*c0[t] + sigmf(af1+bf)*c1[t];
  float h = sigmf(ao)*tanhfast(c);
  cmat[(size_t)(offCur+n)*MEMD + t] = c;
  hmat[(size_t)(offCur+n)*MEMD + t] = h;
}

// ---------------------------------------------------------------------------
// proj = mat @ W2^T + b_attnh  (b_attnh folded in), and colsum = sum_rows(mat).
// Blocks: [0,511) projL rows; 511 colL; [512,1023) projR rows; 1023 colR.
// ---------------------------------------------------------------------------
__global__ void k_proj(const float* __restrict__ W_attnh, const float* __restrict__ b_attnh,
                       const float* __restrict__ matL, const float* __restrict__ matR,
                       float* __restrict__ projL, float* __restrict__ projR,
                       float* __restrict__ colL, float* __restrict__ colR)
{
  int b = blockIdx.x;
  int t = threadIdx.x;
  if (b == 511 || b == 1023){
    const float* mat = (b == 511) ? matL : matR;
    float* col = (b == 511) ? colL : colR;
    float s = 0.f;
    for (int m = 0; m < ROWS; ++m) s += mat[(size_t)m*MEMD + t];
    col[t] = s;
    return;
  }
  bool isL = (b < 511);
  int m = isL ? b : b - 512;
  const float* mat = isL ? matL : matR;
  float* proj = isL ? projL : projR;
  __shared__ float ms[256];
  ms[t] = mat[(size_t)m*MEMD + t];
  __syncthreads();
  const float* w2 = W_attnh + (size_t)t*512 + 256;
  float a = b_attnh[t];
  for (int e = 0; e < 256; ++e) a += ms[e]*w2[e];
  proj[(size_t)m*MEMD + t] = a;
}

// ---------------------------------------------------------------------------
// Attention for one row (one block, 256 threads). hval = this thread's h[t].
// out[t] = colsum[t] - sum_m s[m]*mat[m,t] + h[t]   (sum(s)==1)
// ---------------------------------------------------------------------------
__device__ void attend_row(float hval, float* __restrict__ hout,
                           const float* __restrict__ mat, const float* __restrict__ proj,
                           const float* __restrict__ colsum,
                           const float* __restrict__ W_attnh, const float* __restrict__ Wa)
{
  __shared__ float sh_h[256], sh_hp[256], sh_wa[256], sh_s[512], sh_red[256];
  int t = threadIdx.x;
  sh_h[t] = hval;
  sh_wa[t] = Wa[t];
  __syncthreads();

  // hp[t] = sum_e h[e] * W1[t,e]   (W1 = W_attnh[:, :256])
  const float* w1 = W_attnh + (size_t)t*512;
  float a = 0.f;
  for (int e = 0; e < 256; ++e) a += sh_h[e]*w1[e];
  sh_hp[t] = a;
  __syncthreads();

  // scores for m = t and m = t+256 (m < 511)
  const float* p0 = proj + (size_t)t*MEMD;
  float s0 = 0.f, s1 = -1e30f;
  for (int d = 0; d < 256; ++d) s0 += sh_wa[d]*tanhfast(sh_hp[d] + p0[d]);
  if (t < 255){
    const float* p1 = proj + (size_t)(t+256)*MEMD;
    float acc = 0.f;
    for (int d = 0; d < 256; ++d) acc += sh_wa[d]*tanhfast(sh_hp[d] + p1[d]);
    s1 = acc;
  }

  // softmax over 511 scores
  sh_red[t] = fmaxf(s0, s1); __syncthreads();
  for (int off = 128; off > 0; off >>= 1){
    if (t < off) sh_red[t] = fmaxf(sh_red[t], sh_red[t+off]);
    __syncthreads();
  }
  float M = sh_red[0]; __syncthreads();
  float e0 = __expf(s0 - M);
  float e1 = (t < 255) ? __expf(s1 - M) : 0.f;
  sh_red[t] = e0 + e1; __syncthreads();
  for (int off = 128; off > 0; off >>= 1){
    if (t < off) sh_red[t] += sh_red[t+off];
    __syncthreads();
  }
  float inv = 1.0f/sh_red[0];
  sh_s[t] = e0*inv;
  sh_s[t+256] = e1*inv;   // slot 511 is 0, never read
  __syncthreads();

  float acc = 0.f;
  for (int m = 0; m < ROWS; ++m) acc += sh_s[m]*mat[(size_t)m*MEMD + t];  // coalesced over t
  hout[t] = colsum[t] - acc + hval;
}

// ---------------------------------------------------------------------------
// Initial attend for passes C and D (+ copy initial c from B/A).
// Blocks [0,256): C rows (h0 = matR rows, attends matL); [256,512): D rows.
// ---------------------------------------------------------------------------
__global__ void k_attend_init(const float* __restrict__ W_attnh, const float* __restrict__ Wa,
                              const float* __restrict__ matL, const float* __restrict__ matR,
                              const float* __restrict__ projL, const float* __restrict__ projR,
                              const float* __restrict__ colL, const float* __restrict__ colR,
                              const float* __restrict__ cmatA, const float* __restrict__ cmatB,
                              float* __restrict__ cmatC, float* __restrict__ hC,
                              float* __restrict__ cmatD, float* __restrict__ hD)
{
  int b = blockIdx.x, t = threadIdx.x;
  if (b < 256){
    int r = b;
    cmatC[(size_t)r*MEMD + t] = cmatB[(size_t)r*MEMD + t];
    float hval = matR[(size_t)r*MEMD + t];
    attend_row(hval, hC + (size_t)r*MEMD, matL, projL, colL, W_attnh, Wa);
  } else {
    int r = b - 256;
    cmatD[(size_t)r*MEMD + t] = cmatA[(size_t)r*MEMD + t];
    float hval = matL[(size_t)r*MEMD + t];
    attend_row(hval, hD + (size_t)r*MEMD, matR, projR, colR, W_attnh, Wa);
  }
}

// ---------------------------------------------------------------------------
// Fused tree level + attend for passes C and D.
// Blocks [0,half): pass C (attends matL); [half,2*half): pass D (attends matR).
// ---------------------------------------------------------------------------
__global__ void k_level_att(const float* __restrict__ W_iouh, const float* __restrict__ b_iouh,
                            const float* __restrict__ W_fh, const float* __restrict__ b_fh,
                            const float* __restrict__ W_attnh, const float* __restrict__ Wa,
                            int half, int offPrev, int offCur,
                            float* __restrict__ cmatC, float* __restrict__ hC,
                            const float* __restrict__ matL, const float* __restrict__ projL,
                            const float* __restrict__ colL,
                            float* __restrict__ cmatD, float* __restrict__ hD,
                            const float* __restrict__ matR, const float* __restrict__ projR,
                            const float* __restrict__ colR)
{
  int b = blockIdx.x;
  bool isC = (b < half);
  int n = isC ? b : b - half;
  float* cmat = isC ? cmatC : cmatD;
  float* hmat = isC ? hC : hD;
  const float* mat  = isC ? matL  : matR;
  const float* proj = isC ? projL : projR;
  const float* col  = isC ? colL  : colR;

  const float* h0 = hmat + (size_t)(offPrev + 2*n)*MEMD;
  const float* h1 = h0 + MEMD;
  const float* c0 = cmat + (size_t)(offPrev + 2*n)*MEMD;
  const float* c1 = c0 + MEMD;

  __shared__ float hs0[256], hs1[256], hss[256];
  int t = threadIdx.x;
  float a0 = h0[t], a1 = h1[t];
  hs0[t] = a0; hs1[t] = a1; hss[t] = a0 + a1;
  __syncthreads();

  const float* wi = W_iouh + (size_t)t*256;
  const float* wo = W_iouh + (size_t)(t+256)*256;
  const float* wu = W_iouh + (size_t)(t+512)*256;
  const float* wf = W_fh   + (size_t)t*256;
  float ai=0.f, ao=0.f, au=0.f, af0=0.f, af1=0.f;
  for (int d = 0; d < 256; ++d){
    float s = hss[d];
    ai += s*wi[d];
    ao += s*wo[d];
    au += s*wu[d];
    float w = wf[d];
    af0 += hs0[d]*w;
    af1 += hs1[d]*w;
  }
  ai += b_iouh[t]; ao += b_iouh[t+256]; au += b_iouh[t+512];
  float bf = b_fh[t];
  float c = sigmf(ai)*tanhfast(au) + sigmf(af0+bf)*c0[t] + sigmf(af1+bf)*c1[t];
  float h = sigmf(ao)*tanhfast(c);
  cmat[(size_t)(offCur+n)*MEMD + t] = c;
  __syncthreads();  // hs* dead before attend_row begins

  attend_row(h, hmat + (size_t)(offCur+n)*MEMD, mat, proj, col, W_attnh, Wa);
}

// ---------------------------------------------------------------------------
// Head: lhid/rhid -> v -> sigmoid MLP -> log_softmax (5 outputs, fp32).
// One block, 128 threads.
// ---------------------------------------------------------------------------
__global__ void k_final(const float* __restrict__ W_wh, const float* __restrict__ b_wh,
                        const float* __restrict__ W_wp, const float* __restrict__ b_wp,
                        const float* __restrict__ lh1, const float* __restrict__ rh1,
                        const float* __restrict__ rh2, const float* __restrict__ lh2,
                        float* __restrict__ out)
{
  __shared__ float v[512];
  __shared__ float og[128];
  __shared__ float lg[5];
  int t = threadIdx.x;  // 128 threads
  for (int i = t; i < 256; i += 128){
    float lh = tanhfast(lh1[i] + lh2[i]);
    float rh = tanhfast(rh1[i] + rh2[i]);
    v[i] = lh*rh;
    v[256+i] = fabsf(lh - rh);
  }
  __syncthreads();
  const float* w = W_wh + (size_t)t*512;
  float a = b_wh[t];
  for (int e = 0; e < 512; ++e) a += v[e]*w[e];
  og[t] = sigmf(a);
  __syncthreads();
  if (t < 5){
    float a2 = b_wp[t];
    const float* wp = W_wp + (size_t)t*128;
    for (int j = 0; j < 128; ++j) a2 += og[j]*wp[j];
    lg[t] = a2;
  }
  __syncthreads();
  if (t == 0){
    float M = -1e30f;
    for (int c = 0; c < 5; ++c) M = fmaxf(M, lg[c]);
    float S = 0.f;
    for (int c = 0; c < 5; ++c) S += __expf(lg[c] - M);
    float L = logf(S);
    for (int c = 0; c < 5; ++c) out[c] = lg[c] - M - L;
  }
}

extern "C" void kernel_launch(void* const* d_in, const int* in_sizes, int n_in,
                              void* d_out, int out_size, void* d_ws, size_t ws_size,
                              hipStream_t stream)
{
  const int*   l_idx   = (const int*)  d_in[0];
  const int*   r_idx   = (const int*)  d_in[1];
  const float* emb     = (const float*)d_in[2];
  const float* W_ioux  = (const float*)d_in[3];
  const float* b_ioux  = (const float*)d_in[4];
  const float* W_iouh  = (const float*)d_in[5];
  const float* b_iouh  = (const float*)d_in[6];
  // d_in[7]=W_fx, d_in[8]=b_fx : unused by the reference forward
  const float* W_fh    = (const float*)d_in[9];
  const float* b_fh    = (const float*)d_in[10];
  const float* Wa      = (const float*)d_in[11];
  const float* W_attnh = (const float*)d_in[12];
  const float* b_attnh = (const float*)d_in[13];
  const float* W_wh    = (const float*)d_in[14];
  const float* b_wh    = (const float*)d_in[15];
  const float* W_wp    = (const float*)d_in[16];
  const float* b_wp    = (const float*)d_in[17];

  float* ws = (float*)d_ws;
  const size_t RC = (size_t)ROWS*MEMD;  // 130816 floats
  float* cmatA = ws;           float* matL  = cmatA + RC;
  float* cmatB = matL  + RC;   float* matR  = cmatB + RC;
  float* projL = matR  + RC;   float* projR = projL + RC;
  float* cmatC = projR + RC;   float* hC    = cmatC + RC;
  float* cmatD = hC    + RC;   float* hD    = cmatD + RC;
  float* colL  = hD    + RC;   float* colR  = colL + 256;
  // total: 10*RC + 512 floats ~ 5.3 MB

  static const int offs[9] = {0, 256, 384, 448, 480, 496, 504, 508, 510};

  // Passes A and B (batched): init + 8 levels
  k_init<<<512, 256, 0, stream>>>(l_idx, r_idx, emb, W_ioux, b_ioux, b_iouh,
                                  cmatA, matL, cmatB, matR);
  for (int i = 1; i <= 8; ++i){
    int Nc = 256 >> i;
    k_level<<<2*Nc, 256, 0, stream>>>(W_iouh, b_iouh, W_fh, b_fh,
                                      Nc, offs[i-1], offs[i],
                                      cmatA, matL, cmatB, matR);
  }

  // mat_proj (+b_attnh) and column sums for both mats
  k_proj<<<1024, 256, 0, stream>>>(W_attnh, b_attnh, matL, matR,
                                   projL, projR, colL, colR);

  // Passes C and D (batched): initial attend + 8 fused level+attend
  k_attend_init<<<512, 256, 0, stream>>>(W_attnh, Wa, matL, matR, projL, projR,
                                         colL, colR, cmatA, cmatB,
                                         cmatC, hC, cmatD, hD);
  for (int i = 1; i <= 8; ++i){
    int Nc = 256 >> i;
    k_level_att<<<2*Nc, 256, 0, stream>>>(W_iouh, b_iouh, W_fh, b_fh, W_attnh, Wa,
                                          Nc, offs[i-1], offs[i],
                                          cmatC, hC, matL, projL, colL,
                                          cmatD, hD, matR, projR, colR);
  }

  // Head
  k_final<<<1, 128, 0, stream>>>(W_wh, b_wh, W_wp, b_wp,
                                 matL + (size_t)510*MEMD,  // lh1
                                 hC   + (size_t)510*MEMD,  // rh1
                                 matR + (size_t)510*MEMD,  // rh2
                                 hD   + (size_t)510*MEMD,  // lh2
                                 (float*)d_out);
}

// Round 3
// 1051.399 us; speedup vs baseline: 1.2763x; 1.2763x over previous
//
#include <hip/hip_runtime.h>
#include <hip/hip_bf16.h>

#define MEMD 256
#define ROWS 511   // 256+128+64+32+16+8+4+2+1

__device__ __forceinline__ float sigmf(float x){ return 1.0f/(1.0f+__expf(-x)); }
__device__ __forceinline__ float tanhfast(float x){
  x = fminf(fmaxf(x, -15.0f), 15.0f);
  float e = __expf(2.0f*x);
  return (e-1.0f)/(e+1.0f);
}

// ---------------------------------------------------------------------------
// Prep: transpose all weight matrices so inner matvec loops are coalesced.
//   WxT[d*768+r] = W_ioux[r*300+d]      (768x300 -> 300x768)
//   WiT[d*768+r] = W_iouh[r*256+d]      (768x256 -> 256x768)
//   WfT[d*256+r] = W_fh  [r*256+d]
//   W1T[d*256+r] = W_attnh[r*512+d]          (d<256)
//   W2T[d*256+r] = W_attnh[r*512+256+d]      (d<256)
//   WhT[d*128+r] = W_wh  [r*512+d]      (128x512 -> 512x128)
// ---------------------------------------------------------------------------
__global__ void k_prep(const float* __restrict__ W_ioux, const float* __restrict__ W_iouh,
                       const float* __restrict__ W_fh, const float* __restrict__ W_attnh,
                       const float* __restrict__ W_wh,
                       float* __restrict__ WxT, float* __restrict__ WiT, float* __restrict__ WfT,
                       float* __restrict__ W1T, float* __restrict__ W2T, float* __restrict__ WhT)
{
  int stride = gridDim.x*blockDim.x;
  int i0 = blockIdx.x*blockDim.x + threadIdx.x;
  for (int i = i0; i < 768*300; i += stride){ int r = i/300; int d = i - r*300; WxT[d*768 + r] = W_ioux[i]; }
  for (int i = i0; i < 768*256; i += stride){ int r = i>>8, d = i&255; WiT[d*768 + r] = W_iouh[i]; }
  for (int i = i0; i < 256*256; i += stride){ int r = i>>8, d = i&255; WfT[d*256 + r] = W_fh[i]; }
  for (int i = i0; i < 256*512; i += stride){
    int r = i>>9, d = i&511; float v = W_attnh[i];
    if (d < 256) W1T[d*256 + r] = v; else W2T[(d-256)*256 + r] = v;
  }
  for (int i = i0; i < 128*512; i += stride){ int r = i>>9, d = i&511; WhT[d*128 + r] = W_wh[i]; }
}

// ---------------------------------------------------------------------------
// Init: iou = x @ W_ioux^T + b_ioux + b_iouh -> c0,h0.
// Blocks [0,256): pass A (lx) ; [256,512): pass B (rx). 256 threads.
// ---------------------------------------------------------------------------
__global__ void k_init(const int* __restrict__ l_idx, const int* __restrict__ r_idx,
                       const float* __restrict__ emb, const float* __restrict__ WxT,
                       const float* __restrict__ b_ioux, const float* __restrict__ b_iouh,
                       float* __restrict__ cmatA, float* __restrict__ matL,
                       float* __restrict__ cmatB, float* __restrict__ matR)
{
  int b = blockIdx.x;
  bool isA = (b < 256);
  int n = isA ? b : b - 256;
  int row = isA ? l_idx[n] : r_idx[n];
  float* crow = (isA ? cmatA : cmatB) + (size_t)n*MEMD;
  float* hrow = (isA ? matL  : matR ) + (size_t)n*MEMD;

  __shared__ float xs[304];
  const float* xr = emb + (size_t)row*300;
  for (int d = threadIdx.x; d < 300; d += 256) xs[d] = xr[d];
  __syncthreads();

  int m = threadIdx.x;
  float ai=0.f, ao=0.f, au=0.f;
  for (int d = 0; d < 300; ++d){
    float x = xs[d];
    const float* w = WxT + d*768;
    ai += x*w[m]; ao += x*w[m+256]; au += x*w[m+512];
  }
  ai += b_ioux[m]     + b_iouh[m];
  ao += b_ioux[m+256] + b_iouh[m+256];
  au += b_ioux[m+512] + b_iouh[m+512];
  float c = sigmf(ai)*tanhfast(au);
  float h = sigmf(ao)*tanhfast(c);
  crow[m] = c; hrow[m] = h;
}

// ---------------------------------------------------------------------------
// LSTM level body shared by k_level / k_level_att. 512 threads.
// Group0 (t<256): ai,ao dots. Group1: au,af0,af1 dots. Combine in group0.
// Returns h (valid for t<256; 0 otherwise); writes c to cmat row.
// ---------------------------------------------------------------------------
__device__ __forceinline__ float lstm_level(int t, int offPrev, int offCur, int n,
                                            const float* __restrict__ WiT,
                                            const float* __restrict__ b_iouh,
                                            const float* __restrict__ WfT,
                                            const float* __restrict__ b_fh,
                                            float* __restrict__ cmat,
                                            const float* __restrict__ hmat)
{
  const float* h0 = hmat + (size_t)(offPrev + 2*n)*MEMD;
  const float* h1 = h0 + MEMD;
  const float* c0 = cmat + (size_t)(offPrev + 2*n)*MEMD;
  const float* c1 = c0 + MEMD;

  __shared__ float hs0[256], hs1[256], hss[256], sAu[256], sF0[256], sF1[256];
  if (t < 256){ float a0 = h0[t], a1 = h1[t]; hs0[t]=a0; hs1[t]=a1; hss[t]=a0+a1; }
  __syncthreads();

  float ai=0.f, ao=0.f;
  if (t < 256){
    for (int d = 0; d < 256; ++d){
      float s = hss[d];
      const float* w = WiT + d*768;
      ai += s*w[t]; ao += s*w[t+256];
    }
  } else {
    int u = t - 256;
    float au=0.f, af0=0.f, af1=0.f;
    for (int d = 0; d < 256; ++d){
      float s = hss[d];
      au  += s*WiT[d*768 + 512 + u];
      float wf = WfT[d*256 + u];
      af0 += hs0[d]*wf;
      af1 += hs1[d]*wf;
    }
    sAu[u]=au; sF0[u]=af0; sF1[u]=af1;
  }
  __syncthreads();

  float h = 0.f;
  if (t < 256){
    float i_ = sigmf(ai + b_iouh[t]);
    float o_ = sigmf(ao + b_iouh[256+t]);
    float u_ = tanhfast(sAu[t] + b_iouh[512+t]);
    float bf = b_fh[t];
    float c = i_*u_ + sigmf(sF0[t]+bf)*c0[t] + sigmf(sF1[t]+bf)*c1[t];
    h = o_*tanhfast(c);
    cmat[(size_t)(offCur+n)*MEMD + t] = c;
  }
  return h;
}

// ---------------------------------------------------------------------------
// One tree level for passes A and B (no attention). 512 threads.
// ---------------------------------------------------------------------------
__global__ void k_level(const float* __restrict__ WiT, const float* __restrict__ b_iouh,
                        const float* __restrict__ WfT, const float* __restrict__ b_fh,
                        int half, int offPrev, int offCur,
                        float* __restrict__ cmatA, float* __restrict__ matL,
                        float* __restrict__ cmatB, float* __restrict__ matR)
{
  int b = blockIdx.x;
  bool isA = (b < half);
  int n = isA ? b : b - half;
  float* cmat = isA ? cmatA : cmatB;
  float* hmat = isA ? matL  : matR;
  int t = threadIdx.x;
  float h = lstm_level(t, offPrev, offCur, n, WiT, b_iouh, WfT, b_fh, cmat, hmat);
  if (t < 256) hmat[(size_t)(offCur+n)*MEMD + t] = h;
}

// ---------------------------------------------------------------------------
// projT[t*512+m] = (mat[m] @ W2^T)[t] + b_attnh[t]; colsum[t] = sum_m mat[m][t].
// Blocks: [0,511) projL rows; 511 colL; [512,1023) projR rows; 1023 colR. 256 thr.
// ---------------------------------------------------------------------------
__global__ void k_proj(const float* __restrict__ W2T, const float* __restrict__ b_attnh,
                       const float* __restrict__ matL, const float* __restrict__ matR,
                       float* __restrict__ projTL, float* __restrict__ projTR,
                       float* __restrict__ colL, float* __restrict__ colR)
{
  int b = blockIdx.x;
  int t = threadIdx.x;
  if (b == 511 || b == 1023){
    const float* mat = (b == 511) ? matL : matR;
    float* col = (b == 511) ? colL : colR;
    float s = 0.f;
    for (int m = 0; m < ROWS; ++m) s += mat[(size_t)m*MEMD + t];
    col[t] = s;
    return;
  }
  bool isL = (b < 511);
  int m = isL ? b : b - 512;
  const float* mat = isL ? matL : matR;
  float* projT = isL ? projTL : projTR;
  __shared__ float ms[256];
  ms[t] = mat[(size_t)m*MEMD + t];
  __syncthreads();
  float a = b_attnh[t];
  for (int e = 0; e < 256; ++e) a += ms[e]*W2T[e*256 + t];
  projT[(size_t)t*512 + m] = a;
}

// ---------------------------------------------------------------------------
// Attention for one output row, 512 threads. hval valid for t<256.
// hout[t] = colsum[t] - sum_m s[m]*mat[m][t] + h[t]    (sum s == 1)
// ---------------------------------------------------------------------------
__device__ void attend512(int t, float hval, float* __restrict__ hout,
                          const float* __restrict__ mat, const float* __restrict__ projT,
                          const float* __restrict__ colsum,
                          const float* __restrict__ W1T, const float* __restrict__ Wa)
{
  __shared__ float sh_h[256], sh_hp[256], sh_wa[256], sh_s[512], sh_red[512];
  __shared__ float sh_p0[256], sh_p1[256];
  if (t < 256){ sh_h[t] = hval; sh_wa[t] = Wa[t]; }
  __syncthreads();

  // hp[j] = sum_e h[e]*W1[j][e], split e into two halves across groups
  {
    int g = t>>8, j = t&255;
    float a = 0.f;
    int e0 = g*128;
    for (int e = e0; e < e0+128; ++e) a += sh_h[e]*W1T[e*256 + j];
    if (g == 0) sh_p0[j] = a; else sh_p1[j] = a;
  }
  __syncthreads();
  if (t < 256) sh_hp[t] = sh_p0[t] + sh_p1[t];
  __syncthreads();

  // score for m = t  (coalesced projT reads)
  float s = -1e30f;
  if (t < ROWS){
    float acc = 0.f;
    const float* pt = projT + t;
    for (int d = 0; d < 256; ++d) acc += sh_wa[d]*tanhfast(sh_hp[d] + pt[(size_t)d*512]);
    s = acc;
  }

  // softmax over 511 (thread 511 holds -1e30 -> e=0)
  sh_red[t] = s; __syncthreads();
  for (int off = 256; off > 0; off >>= 1){
    if (t < off) sh_red[t] = fmaxf(sh_red[t], sh_red[t+off]);
    __syncthreads();
  }
  float M = sh_red[0]; __syncthreads();
  float e = (t < ROWS) ? __expf(s - M) : 0.f;
  sh_red[t] = e; __syncthreads();
  for (int off = 256; off > 0; off >>= 1){
    if (t < off) sh_red[t] += sh_red[t+off];
    __syncthreads();
  }
  float inv = 1.0f/sh_red[0];
  sh_s[t] = e*inv;
  __syncthreads();

  // weighted sum, m split across groups (coalesced mat reads)
  {
    int g = t>>8, j = t&255;
    float acc = 0.f;
    int m0 = g*256, mend = g ? ROWS : 256;
    for (int m = m0; m < mend; ++m) acc += sh_s[m]*mat[(size_t)m*MEMD + j];
    if (g == 0) sh_p0[j] = acc; else sh_p1[j] = acc;
  }
  __syncthreads();
  if (t < 256) hout[t] = colsum[t] - (sh_p0[t] + sh_p1[t]) + sh_h[t];
}

// ---------------------------------------------------------------------------
// Initial attend for passes C and D (+ copy initial c from B/A). 512 threads.
// Blocks [0,256): C rows (h0 = matR rows, attends matL); [256,512): D rows.
// ---------------------------------------------------------------------------
__global__ void k_attend_init(const float* __restrict__ W1T, const float* __restrict__ Wa,
                              const float* __restrict__ matL, const float* __restrict__ matR,
                              const float* __restrict__ projTL, const float* __restrict__ projTR,
                              const float* __restrict__ colL, const float* __restrict__ colR,
                              const float* __restrict__ cmatA, const float* __restrict__ cmatB,
                              float* __restrict__ cmatC, float* __restrict__ hC,
                              float* __restrict__ cmatD, float* __restrict__ hD)
{
  int b = blockIdx.x, t = threadIdx.x;
  bool isC = (b < 256);
  int r = isC ? b : b - 256;
  const float* csrc = isC ? cmatB : cmatA;
  float* cdst = isC ? cmatC : cmatD;
  const float* hsrc = isC ? matR : matL;
  float* hdst = (isC ? hC : hD) + (size_t)r*MEMD;
  float hval = 0.f;
  if (t < 256){
    cdst[(size_t)r*MEMD + t] = csrc[(size_t)r*MEMD + t];
    hval = hsrc[(size_t)r*MEMD + t];
  }
  attend512(t, hval, hdst,
            isC ? matL : matR, isC ? projTL : projTR, isC ? colL : colR, W1T, Wa);
}

// ---------------------------------------------------------------------------
// Fused tree level + attend for passes C and D. 512 threads.
// ---------------------------------------------------------------------------
__global__ void k_level_att(const float* __restrict__ WiT, const float* __restrict__ b_iouh,
                            const float* __restrict__ WfT, const float* __restrict__ b_fh,
                            const float* __restrict__ W1T, const float* __restrict__ Wa,
                            int half, int offPrev, int offCur,
                            float* __restrict__ cmatC, float* __restrict__ hC,
                            const float* __restrict__ matL, const float* __restrict__ projTL,
                            const float* __restrict__ colL,
                            float* __restrict__ cmatD, float* __restrict__ hD,
                            const float* __restrict__ matR, const float* __restrict__ projTR,
                            const float* __restrict__ colR)
{
  int b = blockIdx.x;
  bool isC = (b < half);
  int n = isC ? b : b - half;
  float* cmat = isC ? cmatC : cmatD;
  float* hmat = isC ? hC : hD;
  int t = threadIdx.x;
  float h = lstm_level(t, offPrev, offCur, n, WiT, b_iouh, WfT, b_fh, cmat, hmat);
  attend512(t, h, hmat + (size_t)(offCur+n)*MEMD,
            isC ? matL : matR, isC ? projTL : projTR, isC ? colL : colR, W1T, Wa);
}

// ---------------------------------------------------------------------------
// Head: lhid/rhid -> v -> sigmoid MLP -> log_softmax (5 outputs, fp32).
// One block, 128 threads, coalesced WhT.
// ---------------------------------------------------------------------------
__global__ void k_final(const float* __restrict__ WhT, const float* __restrict__ b_wh,
                        const float* __restrict__ W_wp, const float* __restrict__ b_wp,
                        const float* __restrict__ lh1, const float* __restrict__ rh1,
                        const float* __restrict__ rh2, const float* __restrict__ lh2,
                        float* __restrict__ out)
{
  __shared__ float v[512];
  __shared__ float og[128];
  __shared__ float lg[5];
  int t = threadIdx.x;  // 128 threads
  for (int i = t; i < 256; i += 128){
    float lh = tanhfast(lh1[i] + lh2[i]);
    float rh = tanhfast(rh1[i] + rh2[i]);
    v[i] = lh*rh;
    v[256+i] = fabsf(lh - rh);
  }
  __syncthreads();
  float a = b_wh[t];
  for (int e = 0; e < 512; ++e) a += v[e]*WhT[e*128 + t];
  og[t] = sigmf(a);
  __syncthreads();
  if (t < 5){
    float a2 = b_wp[t];
    const float* wp = W_wp + (size_t)t*128;
    for (int j = 0; j < 128; ++j) a2 += og[j]*wp[j];
    lg[t] = a2;
  }
  __syncthreads();
  if (t == 0){
    float M = -1e30f;
    for (int c = 0; c < 5; ++c) M = fmaxf(M, lg[c]);
    float S = 0.f;
    for (int c = 0; c < 5; ++c) S += __expf(lg[c] - M);
    float L = logf(S);
    for (int c = 0; c < 5; ++c) out[c] = lg[c] - M - L;
  }
}

extern "C" void kernel_launch(void* const* d_in, const int* in_sizes, int n_in,
                              void* d_out, int out_size, void* d_ws, size_t ws_size,
                              hipStream_t stream)
{
  const int*   l_idx   = (const int*)  d_in[0];
  const int*   r_idx   = (const int*)  d_in[1];
  const float* emb     = (const float*)d_in[2];
  const float* W_ioux  = (const float*)d_in[3];
  const float* b_ioux  = (const float*)d_in[4];
  const float* W_iouh  = (const float*)d_in[5];
  const float* b_iouh  = (const float*)d_in[6];
  // d_in[7]=W_fx, d_in[8]=b_fx : unused by the reference forward
  const float* W_fh    = (const float*)d_in[9];
  const float* b_fh    = (const float*)d_in[10];
  const float* Wa      = (const float*)d_in[11];
  const float* W_attnh = (const float*)d_in[12];
  const float* b_attnh = (const float*)d_in[13];
  const float* W_wh    = (const float*)d_in[14];
  const float* b_wh    = (const float*)d_in[15];
  const float* W_wp    = (const float*)d_in[16];
  const float* b_wp    = (const float*)d_in[17];

  float* ws = (float*)d_ws;
  const size_t RC = (size_t)ROWS*MEMD;  // 130816 floats
  float* cmatA  = ws;            float* matL   = cmatA  + RC;
  float* cmatB  = matL   + RC;   float* matR   = cmatB  + RC;
  float* cmatC  = matR   + RC;   float* hC     = cmatC  + RC;
  float* cmatD  = hC     + RC;   float* hD     = cmatD  + RC;
  float* projTL = hD     + RC;                       // 256*512
  float* projTR = projTL + 256*512;                  // 256*512
  float* colL   = projTR + 256*512;                  // 256
  float* colR   = colL + 256;                        // 256
  float* WxT    = colR + 256;                        // 300*768
  float* WiT    = WxT + 300*768;                     // 256*768
  float* WfT    = WiT + 256*768;                     // 256*256
  float* W1T    = WfT + 256*256;                     // 256*256
  float* W2T    = W1T + 256*256;                     // 256*256
  float* WhT    = W2T + 256*256;                     // 512*128
  // total ~2.0M floats ~ 8.0 MB

  static const int offs[9] = {0, 256, 384, 448, 480, 496, 504, 508, 510};

  // Weight transposes (coalesced inner loops everywhere else)
  k_prep<<<512, 256, 0, stream>>>(W_ioux, W_iouh, W_fh, W_attnh, W_wh,
                                  WxT, WiT, WfT, W1T, W2T, WhT);

  // Passes A and B (batched): init + 8 levels
  k_init<<<512, 256, 0, stream>>>(l_idx, r_idx, emb, WxT, b_ioux, b_iouh,
                                  cmatA, matL, cmatB, matR);
  for (int i = 1; i <= 8; ++i){
    int Nc = 256 >> i;
    k_level<<<2*Nc, 512, 0, stream>>>(WiT, b_iouh, WfT, b_fh,
                                      Nc, offs[i-1], offs[i],
                                      cmatA, matL, cmatB, matR);
  }

  // mat_proj^T (+b_attnh) and column sums for both mats
  k_proj<<<1024, 256, 0, stream>>>(W2T, b_attnh, matL, matR,
                                   projTL, projTR, colL, colR);

  // Passes C and D (batched): initial attend + 8 fused level+attend
  k_attend_init<<<512, 512, 0, stream>>>(W1T, Wa, matL, matR, projTL, projTR,
                                         colL, colR, cmatA, cmatB,
                                         cmatC, hC, cmatD, hD);
  for (int i = 1; i <= 8; ++i){
    int Nc = 256 >> i;
    k_level_att<<<2*Nc, 512, 0, stream>>>(WiT, b_iouh, WfT, b_fh, W1T, Wa,
                                          Nc, offs[i-1], offs[i],
                                          cmatC, hC, matL, projTL, colL,
                                          cmatD, hD, matR, projTR, colR);
  }

  // Head
  k_final<<<1, 128, 0, stream>>>(WhT, b_wh, W_wp, b_wp,
                                 matL + (size_t)510*MEMD,  // lh1
                                 hC   + (size_t)510*MEMD,  // rh1
                                 matR + (size_t)510*MEMD,  // rh2
                                 hD   + (size_t)510*MEMD,  // lh2
                                 (float*)d_out);
}